// Round 4
// baseline (79.559 us; speedup 1.0000x reference)
//
#include <hip/hip_runtime.h>

// Difference3DCostVolume: out[b,c,d,h,w] = l[b,c,h,w] - r[b,c,h,w-d], pad 1.0 for w<d
// Shapes: l,r [B=2, C=32, H=128, W=240] f32; out [B, C, D=48, H, W] f32.
// Write-BW bound: 377.5 MB out. Fill-kernel ceiling on this chip: ~6.9 TB/s -> ~57-62 us.
//
// R3: block = (bc, 16-row h-group), 960 threads (15 waves, all 64 lanes active:
// 16 rows x 60 float4 = 960). r rows staged in front-padded LDS. Per d the
// block writes a contiguous 15 KB slab (dense 1 KB wave-stores, 100% lanes).
// Grid = 64 bc x 8 hgroups = 512 blocks = 2 blocks/CU, 30 waves/CU.

#define MAX_DISP 48
#define HH 128
#define WW 240
#define NV 60              // float4 per row
#define PAD4 12            // 12 float4 = 48 floats front pad per row
#define ROW4 (PAD4 + NV)   // 72 float4 per LDS row
#define HG 16              // rows per block

typedef float f32x4 __attribute__((ext_vector_type(4)));

__global__ __launch_bounds__(960) void costvol_kernel(
    const f32x4* __restrict__ l4,
    const f32x4* __restrict__ r4,
    f32x4* __restrict__ out4)
{
    __shared__ f32x4 r_lds[HG * ROW4];   // 16 rows x 72 f32x4 = 18.4 KB

    const int bc  = blockIdx.x & 63;     // 0..63
    const int hg  = blockIdx.x >> 6;     // 0..7
    const int h0  = hg * HG;
    const int tid = threadIdx.x;         // 0..959
    const int hl  = tid / NV;            // 0..15 row within group
    const int v   = tid % NV;            // 0..59 float4 within row

    // zero the 12-f32x4 front pad of each row (192 slots)
    if (tid < HG * PAD4) {
        r_lds[(tid / PAD4) * ROW4 + (tid % PAD4)] = (f32x4){0.f, 0.f, 0.f, 0.f};
    }
    // stage 16 rows of r: one f32x4 per thread, coalesced
    const size_t in_base = ((size_t)bc * HH + h0) * NV;   // f32x4 index
    r_lds[hl * ROW4 + PAD4 + v] = r4[in_base + tid];
    // l slab, register-resident
    const f32x4 lv = l4[in_base + tid];
    __syncthreads();

    const int w0 = 4 * v;
    // out f32x4 index for d=0: ((bc*48 + 0)*128 + h0 + hl)*60 + v
    size_t ob = ((size_t)bc * MAX_DISP * HH + h0 + hl) * NV + v;
    const size_t dstride4 = (size_t)HH * NV;   // 7680 f32x4 per d

    #pragma unroll
    for (int k = 0; k < MAX_DISP / 4; ++k) {   // d-group d = 4k..4k+3
        const int d0 = 4 * k;
        const f32x4 A = r_lds[hl * ROW4 + PAD4 + v - k];       // r[w0-d0 ..]
        const f32x4 B = r_lds[hl * ROW4 + PAD4 + v - k - 1];   // r[w0-d0-4 ..]

        #pragma unroll
        for (int s = 0; s < 4; ++s) {          // d = d0 + s
            f32x4 o;
            #pragma unroll
            for (int j = 0; j < 4; ++j) {      // w = w0 + j
                const int src = j - s;         // compile-time
                float rv = (src >= 0) ? A[src] : B[4 + src];
                o[j] = (w0 + j >= d0 + s) ? (lv[j] - rv) : 1.0f;
            }
            __builtin_nontemporal_store(o, &out4[ob + (size_t)(d0 + s) * dstride4]);
        }
    }
}

extern "C" void kernel_launch(void* const* d_in, const int* in_sizes, int n_in,
                              void* d_out, int out_size, void* d_ws, size_t ws_size,
                              hipStream_t stream) {
    const f32x4* l4 = (const f32x4*)d_in[0];
    const f32x4* r4 = (const f32x4*)d_in[1];
    f32x4* out4 = (f32x4*)d_out;

    const int nblocks = 64 * (HH / HG);   // 512
    costvol_kernel<<<nblocks, 960, 0, stream>>>(l4, r4, out4);
}